// Round 1
// baseline (2566.307 us; speedup 1.0000x reference)
//
#include <hip/hip_runtime.h>
#include <hip/hip_bf16.h>

// Sinkhorn distance, N=4096, D=2, P=1, eps=0.1, 50 iters.
// u_i = eps*log_mu - eps*LSE_j((v_j - C_ij)/eps);  v_j symmetric with fresh u.
// C recomputed on the fly (3 VALU). No max-subtraction needed (args bounded).
// One persistent cooperative kernel, grid barrier = monotonic atomic counter.

#define NPTS      4096
#define EPS_F     0.1f
#define S_L2E     14.426950408889634f   /* log2(e)/eps */
#define A_LOGMU   (-0.8317725207f)      /* eps * ln(1/N + 1e-8) */
#define N_ITER    50
#define NBLK      256
#define TPB       256
#define WPB       (TPB / 64)            /* waves per block = 4 */
#define RPW       4                     /* rows per wave     */
#define NJT       (NPTS / 256)          /* j-tiles: 64 lanes x 4 j = 256 cols */

typedef float f4u __attribute__((ext_vector_type(4), aligned(4)));

__device__ __forceinline__ float fexp2(float x) {
#if __has_builtin(__builtin_amdgcn_exp2f)
  return __builtin_amdgcn_exp2f(x);
#else
  float r;
  asm("v_exp_f32 %0, %1" : "=v"(r) : "v"(x));
  return r;
#endif
}

__device__ __forceinline__ float wave_sum64(float x) {
#pragma unroll
  for (int off = 32; off > 0; off >>= 1) x += __shfl_xor(x, off, 64);
  return x;
}

__device__ __forceinline__ void grid_barrier(int* counter, int target) {
  __syncthreads();
  if (threadIdx.x == 0) {
    __threadfence();  // release: flush this block's u/v stores device-wide
    __hip_atomic_fetch_add(counter, 1, __ATOMIC_ACQ_REL, __HIP_MEMORY_SCOPE_AGENT);
    while (__hip_atomic_load(counter, __ATOMIC_ACQUIRE, __HIP_MEMORY_SCOPE_AGENT) < target)
      __builtin_amdgcn_s_sleep(4);
    __threadfence();  // acquire: invalidate stale L1/L2 lines before re-reading u/v
  }
  __syncthreads();
}

// One half-iteration: for RPW rows of `rowp`, reduce over all cols of `colp`:
//   wout[row] = A_LOGMU - eps * ln( sum_j exp2((win[j] - C(row,j)) * S_L2E) )
__device__ __forceinline__ void half_phase(const float* __restrict__ rowp,
                                           const float* __restrict__ colp,
                                           const float* __restrict__ win,
                                           float* __restrict__ wout,
                                           int wave, int lane) {
  const int row0 = wave * RPW;
  float rx[RPW], ry[RPW], acc[RPW];
#pragma unroll
  for (int r = 0; r < RPW; ++r) {
    rx[r]  = rowp[(row0 + r) * 2 + 0];
    ry[r]  = rowp[(row0 + r) * 2 + 1];
    acc[r] = 0.f;
  }
  const float4* w4 = (const float4*)win;
  const float4* p4 = (const float4*)colp;
#pragma unroll 4
  for (int jt = 0; jt < NJT; ++jt) {
    const int j4 = jt * 256 + lane * 4;
    const float4 wj = w4[j4 >> 2];            // v[j..j+3]
    const float4 pa = p4[j4 >> 1];            // (y0,y1) for j, j+1
    const float4 pb = p4[(j4 >> 1) + 1];      // (y0,y1) for j+2, j+3
    const float ws0 = wj.x * S_L2E, ws1 = wj.y * S_L2E;
    const float ws2 = wj.z * S_L2E, ws3 = wj.w * S_L2E;
#pragma unroll
    for (int r = 0; r < RPW; ++r) {
      const float c0 = fabsf(rx[r] - pa.x) + fabsf(ry[r] - pa.y);
      const float c1 = fabsf(rx[r] - pa.z) + fabsf(ry[r] - pa.w);
      const float c2 = fabsf(rx[r] - pb.x) + fabsf(ry[r] - pb.y);
      const float c3 = fabsf(rx[r] - pb.z) + fabsf(ry[r] - pb.w);
      const float e0 = fexp2(ws0 - c0 * S_L2E);
      const float e1 = fexp2(ws1 - c1 * S_L2E);
      const float e2 = fexp2(ws2 - c2 * S_L2E);
      const float e3 = fexp2(ws3 - c3 * S_L2E);
      acc[r] += (e0 + e1) + (e2 + e3);
    }
  }
#pragma unroll
  for (int r = 0; r < RPW; ++r) {
    const float S = wave_sum64(acc[r]);
    if (lane == 0) wout[row0 + r] = A_LOGMU - EPS_F * __logf(S);
  }
}

__global__ void __launch_bounds__(TPB, 1)
sinkhorn_main(const float* __restrict__ x, const float* __restrict__ y,
              float* __restrict__ u, float* __restrict__ v,
              float* __restrict__ out, int* __restrict__ counter) {
  const int lane = threadIdx.x & 63;
  const int wave = blockIdx.x * WPB + (threadIdx.x >> 6);
  int target = 0;
  for (int it = 0; it < N_ITER; ++it) {
    half_phase(x, y, v, u, wave, lane);   // update u (rows = x, cols = y)
    target += NBLK;
    grid_barrier(counter, target);
    half_phase(y, x, u, v, wave, lane);   // update v (rows = y, cols = x)
    target += NBLK;
    grid_barrier(counter, target);
  }

  // ---- output phase: cost (out[0]), pi (out[1..]), C (out[1+N*N..]) ----
  float* __restrict__ pi = out + 1;
  float* __restrict__ cm = out + 1 + (size_t)NPTS * NPTS;
  const int row0 = wave * RPW;
  float rx[RPW], ry[RPW], ub[RPW];
#pragma unroll
  for (int r = 0; r < RPW; ++r) {
    rx[r] = x[(row0 + r) * 2 + 0];
    ry[r] = x[(row0 + r) * 2 + 1];
    ub[r] = u[row0 + r] * S_L2E;
  }
  const float4* w4 = (const float4*)v;
  const float4* p4 = (const float4*)y;
  float cost0 = 0.f, cost1 = 0.f, cost2 = 0.f, cost3 = 0.f;
#pragma unroll 2
  for (int jt = 0; jt < NJT; ++jt) {
    const int j4 = jt * 256 + lane * 4;
    const float4 wj = w4[j4 >> 2];
    const float4 pa = p4[j4 >> 1];
    const float4 pb = p4[(j4 >> 1) + 1];
    const float ws0 = wj.x * S_L2E, ws1 = wj.y * S_L2E;
    const float ws2 = wj.z * S_L2E, ws3 = wj.w * S_L2E;
#pragma unroll
    for (int r = 0; r < RPW; ++r) {
      const float c0 = fabsf(rx[r] - pa.x) + fabsf(ry[r] - pa.y);
      const float c1 = fabsf(rx[r] - pa.z) + fabsf(ry[r] - pa.w);
      const float c2 = fabsf(rx[r] - pb.x) + fabsf(ry[r] - pb.y);
      const float c3 = fabsf(rx[r] - pb.z) + fabsf(ry[r] - pb.w);
      const float p0 = fexp2((ub[r] + ws0) - c0 * S_L2E);
      const float p1 = fexp2((ub[r] + ws1) - c1 * S_L2E);
      const float p2 = fexp2((ub[r] + ws2) - c2 * S_L2E);
      const float p3 = fexp2((ub[r] + ws3) - c3 * S_L2E);
      cost0 = fmaf(p0, c0, cost0);
      cost1 = fmaf(p1, c1, cost1);
      cost2 = fmaf(p2, c2, cost2);
      cost3 = fmaf(p3, c3, cost3);
      const size_t base = (size_t)(row0 + r) * NPTS + j4;
      f4u pv; pv.x = p0; pv.y = p1; pv.z = p2; pv.w = p3;
      f4u cv; cv.x = c0; cv.y = c1; cv.z = c2; cv.w = c3;
      *(f4u*)(pi + base) = pv;   // out+1 base is only 4B-aligned; f4u is aligned(4)
      *(f4u*)(cm + base) = cv;
    }
  }
  float cost = wave_sum64((cost0 + cost1) + (cost2 + cost3));
  if (lane == 0) atomicAdd(out, cost);
}

__global__ void sinkhorn_init(float* __restrict__ v, int* __restrict__ counter,
                              float* __restrict__ out) {
  const int i = blockIdx.x * blockDim.x + threadIdx.x;
  if (i < NPTS) v[i] = 0.f;
  if (i == 0) { *counter = 0; out[0] = 0.f; }
}

extern "C" void kernel_launch(void* const* d_in, const int* in_sizes, int n_in,
                              void* d_out, int out_size, void* d_ws, size_t ws_size,
                              hipStream_t stream) {
  const float* x = (const float*)d_in[0];
  const float* y = (const float*)d_in[1];
  float* u = (float*)d_ws;
  float* v = u + NPTS;
  int* counter = (int*)(u + 2 * NPTS);
  float* out = (float*)d_out;

  sinkhorn_init<<<dim3((NPTS + TPB - 1) / TPB), dim3(TPB), 0, stream>>>(v, counter, out);

  void* args[6];
  args[0] = (void*)&x;
  args[1] = (void*)&y;
  args[2] = (void*)&u;
  args[3] = (void*)&v;
  args[4] = (void*)&out;
  args[5] = (void*)&counter;
  hipLaunchCooperativeKernel((void*)sinkhorn_main, dim3(NBLK), dim3(TPB),
                             args, 0, stream);
}

// Round 2
// 1128.352 us; speedup vs baseline: 2.2744x; 2.2744x over previous
//
#include <hip/hip_runtime.h>

// Sinkhorn, N=4096, D=2, P=1, eps=0.1, 50 iters — persistent cooperative kernel.
// u_i = eps*log_mu - eps*ln sum_j exp((v_j - C_ij)/eps); v symmetric with fresh u.
// All exp args computed in log2-scaled space: arg = W_j - |RX_i - C0_j| - |RY_i - C1_j|
// where every coordinate/potential is pre-multiplied by S_L2E = log2(e)/eps.
//
// Key design vs round 1 (2566 us, VALUBusy 11.6%):
//  - NO __threadfence (was buffer_wbl2/buffer_inv = full L2 writeback+invalidate
//    per block per barrier -> ~20 us/barrier + evicted all cached data).
//  - u/v travel ONLY through sc0/sc1 coherent ops (__hip_atomic_* RELAXED AGENT):
//    MALL is the coherence point, L2 never holds them -> no fences needed.
//    __syncthreads() drains each wave's vmcnt before the counter RMW (release),
//    and coherent loads after the spin see fresh MALL data (acquire).
//  - Hot data (win + column coords, scaled) staged in 48 KB LDS per phase.
//  - 512 thr/block (2 waves/SIMD), wave pairs split columns, 4 rows/wave.

#define NPTS    4096
#define EPS_F   0.1f
#define S_L2E   14.426950408889634f     /* log2(e)/eps */
#define INV_SL  0.0693147180559945f     /* 1/S_L2E = eps*ln2 */
#define A_LOGMU (-0.8317725207f)        /* eps * ln(1/N + 1e-8) */
#define N_ITER  50
#define NBLK    256
#define TPB     512
#define WPB     (TPB / 64)              /* 8 waves/block */
#define RPW     4                       /* rows per wave (wave-pair shares rows) */
#define HALFC   2048                    /* columns per wave (pair splits 4096) */
#define NJT     (HALFC / 256)           /* 8 j-tiles of 64 lanes x 4 cols */

typedef float f4u __attribute__((ext_vector_type(4), aligned(4)));

__device__ __forceinline__ float fexp2(float x) {
#if __has_builtin(__builtin_amdgcn_exp2f)
  return __builtin_amdgcn_exp2f(x);
#else
  float r;
  asm("v_exp_f32 %0, %1" : "=v"(r) : "v"(x));
  return r;
#endif
}

__device__ __forceinline__ float coh_load(const float* p) {
  return __hip_atomic_load(p, __ATOMIC_RELAXED, __HIP_MEMORY_SCOPE_AGENT);
}
__device__ __forceinline__ void coh_store(float* p, float x) {
  __hip_atomic_store(p, x, __ATOMIC_RELAXED, __HIP_MEMORY_SCOPE_AGENT);
}

__device__ __forceinline__ float wave_sum64(float x) {
#pragma unroll
  for (int off = 32; off > 0; off >>= 1) x += __shfl_xor(x, off, 64);
  return x;
}

// Fence-free grid barrier: __syncthreads drains this block's coherent stores
// (compiler emits s_waitcnt vmcnt(0) before s_barrier); counter lives at MALL.
__device__ __forceinline__ void grid_barrier(int* c, int target) {
  __syncthreads();
  if (threadIdx.x == 0) {
    __hip_atomic_fetch_add(c, 1, __ATOMIC_RELAXED, __HIP_MEMORY_SCOPE_AGENT);
    while (__hip_atomic_load(c, __ATOMIC_RELAXED, __HIP_MEMORY_SCOPE_AGENT) < target)
      __builtin_amdgcn_s_sleep(2);
  }
  __syncthreads();
}

// Stage win (coherent) and column coords (plain, L2-cached) into LDS, scaled.
__device__ __forceinline__ void stage(const float* __restrict__ win,
                                      const float* __restrict__ colp,
                                      float* __restrict__ sW,
                                      float* __restrict__ sC0,
                                      float* __restrict__ sC1, int tid) {
#pragma unroll
  for (int t = 0; t < NPTS / TPB; ++t) {
    const int idx = t * TPB + tid;
    const float  w  = coh_load(win + idx);
    const float2 cp = ((const float2*)colp)[idx];
    sW[idx]  = w * S_L2E;
    sC0[idx] = cp.x * S_L2E;
    sC1[idx] = cp.y * S_L2E;
  }
  __syncthreads();
}

// One half-iteration over this wave's RPW rows x HALFC cols; wave pairs combine
// partials in LDS; threads 0..15 write the block's 16 row results coherently.
__device__ __forceinline__ void phase(const float* __restrict__ rx,
                                      const float* __restrict__ ry,
                                      const float* __restrict__ sW,
                                      const float* __restrict__ sC0,
                                      const float* __restrict__ sC1,
                                      float (*sPart)[RPW],
                                      float* __restrict__ wout,
                                      int row0blk, int wv, int lane, int tid) {
  const int base = (wv & 1) * HALFC + lane * 4;
  float acc[RPW];
#pragma unroll
  for (int r = 0; r < RPW; ++r) acc[r] = 0.f;
#pragma unroll
  for (int jt = 0; jt < NJT; ++jt) {
    const int j = base + jt * 256;
    const float4 W  = *(const float4*)(sW + j);
    const float4 C0 = *(const float4*)(sC0 + j);
    const float4 C1 = *(const float4*)(sC1 + j);
#pragma unroll
    for (int r = 0; r < RPW; ++r) {
      const float a0 = (W.x - fabsf(rx[r] - C0.x)) - fabsf(ry[r] - C1.x);
      const float a1 = (W.y - fabsf(rx[r] - C0.y)) - fabsf(ry[r] - C1.y);
      const float a2 = (W.z - fabsf(rx[r] - C0.z)) - fabsf(ry[r] - C1.z);
      const float a3 = (W.w - fabsf(rx[r] - C0.w)) - fabsf(ry[r] - C1.w);
      acc[r] += (fexp2(a0) + fexp2(a1)) + (fexp2(a2) + fexp2(a3));
    }
  }
#pragma unroll
  for (int r = 0; r < RPW; ++r) {
    const float S = wave_sum64(acc[r]);
    if (lane == 0) sPart[wv][r] = S;
  }
  __syncthreads();
  if (tid < 16) {
    const int p = tid >> 2, r = tid & 3;
    const float S = sPart[2 * p][r] + sPart[2 * p + 1][r];
    coh_store(wout + row0blk + p * 4 + r, A_LOGMU - EPS_F * __logf(S));
  }
}

__global__ void __launch_bounds__(TPB, 2)
sinkhorn_main(const float* __restrict__ x, const float* __restrict__ y,
              float* __restrict__ u, float* __restrict__ v,
              float* __restrict__ out, int* __restrict__ counter) {
  __shared__ float sW[NPTS], sC0[NPTS], sC1[NPTS];
  __shared__ float sPart[WPB][RPW];
  __shared__ float sCost[WPB];

  const int tid  = threadIdx.x;
  const int wv   = tid >> 6;
  const int lane = tid & 63;
  const int row0blk = blockIdx.x * (WPB / 2) * RPW;        // 16 rows per block
  const int row0 = row0blk + (wv >> 1) * RPW;              // this wave's rows

  // Row coordinates (constant all session), pre-scaled, in registers.
  float rxu[RPW], ryu[RPW], rxv[RPW], ryv[RPW];
#pragma unroll
  for (int r = 0; r < RPW; ++r) {
    const float2 xr = ((const float2*)x)[row0 + r];
    const float2 yr = ((const float2*)y)[row0 + r];
    rxu[r] = xr.x * S_L2E;  ryu[r] = xr.y * S_L2E;
    rxv[r] = yr.x * S_L2E;  ryv[r] = yr.y * S_L2E;
  }

  int target = 0;
  for (int it = 0; it < N_ITER; ++it) {
    target += NBLK;  grid_barrier(counter, target);
    stage(v, y, sW, sC0, sC1, tid);                         // cols = y, win = v
    phase(rxu, ryu, sW, sC0, sC1, sPart, u, row0blk, wv, lane, tid);
    target += NBLK;  grid_barrier(counter, target);
    stage(u, x, sW, sC0, sC1, tid);                         // cols = x, win = u
    phase(rxv, ryv, sW, sC0, sC1, sPart, v, row0blk, wv, lane, tid);
  }
  target += NBLK;  grid_barrier(counter, target);
  stage(v, y, sW, sC0, sC1, tid);                           // final v, y cols

  // ---- output: out[0]=cost, out[1..]=pi, out[1+N*N..]=C ----
  float* __restrict__ pi = out + 1;
  float* __restrict__ cm = out + 1 + (size_t)NPTS * NPTS;
  float uu[RPW];
#pragma unroll
  for (int r = 0; r < RPW; ++r) uu[r] = coh_load(u + row0 + r) * S_L2E;

  const int base = (wv & 1) * HALFC + lane * 4;
  float costacc = 0.f;
#pragma unroll 2
  for (int jt = 0; jt < NJT; ++jt) {
    const int j = base + jt * 256;
    const float4 W  = *(const float4*)(sW + j);
    const float4 C0 = *(const float4*)(sC0 + j);
    const float4 C1 = *(const float4*)(sC1 + j);
#pragma unroll
    for (int r = 0; r < RPW; ++r) {
      const float s0 = fabsf(rxu[r] - C0.x) + fabsf(ryu[r] - C1.x);
      const float s1 = fabsf(rxu[r] - C0.y) + fabsf(ryu[r] - C1.y);
      const float s2 = fabsf(rxu[r] - C0.z) + fabsf(ryu[r] - C1.z);
      const float s3 = fabsf(rxu[r] - C0.w) + fabsf(ryu[r] - C1.w);
      const float p0 = fexp2((uu[r] + W.x) - s0);
      const float p1 = fexp2((uu[r] + W.y) - s1);
      const float p2 = fexp2((uu[r] + W.z) - s2);
      const float p3 = fexp2((uu[r] + W.w) - s3);
      costacc = fmaf(p0, s0, costacc);
      costacc = fmaf(p1, s1, costacc);
      costacc = fmaf(p2, s2, costacc);
      costacc = fmaf(p3, s3, costacc);
      const size_t off = (size_t)(row0 + r) * NPTS + j;
      f4u pv; pv.x = p0; pv.y = p1; pv.z = p2; pv.w = p3;
      f4u cv; cv.x = s0 * INV_SL; cv.y = s1 * INV_SL;
      cv.z = s2 * INV_SL; cv.w = s3 * INV_SL;
      *(f4u*)(pi + off) = pv;   // out+1 base is 4B-aligned; f4u is aligned(4)
      *(f4u*)(cm + off) = cv;
    }
  }
  const float cw = wave_sum64(costacc);
  if (lane == 0) sCost[wv] = cw;
  __syncthreads();
  if (tid == 0) {
    float c = 0.f;
#pragma unroll
    for (int w = 0; w < WPB; ++w) c += sCost[w];
    atomicAdd(out, c * INV_SL);
  }
}

__global__ void sinkhorn_init(float* __restrict__ v, int* __restrict__ counter,
                              float* __restrict__ out) {
  const int i = blockIdx.x * blockDim.x + threadIdx.x;
  if (i < NPTS) coh_store(v + i, 0.f);
  if (i == 0) {
    __hip_atomic_store(counter, 0, __ATOMIC_RELAXED, __HIP_MEMORY_SCOPE_AGENT);
    out[0] = 0.f;
  }
}

extern "C" void kernel_launch(void* const* d_in, const int* in_sizes, int n_in,
                              void* d_out, int out_size, void* d_ws, size_t ws_size,
                              hipStream_t stream) {
  const float* x = (const float*)d_in[0];
  const float* y = (const float*)d_in[1];
  float* u = (float*)d_ws;
  float* v = u + NPTS;
  int* counter = (int*)(u + 2 * NPTS);
  float* out = (float*)d_out;

  sinkhorn_init<<<dim3(16), dim3(256), 0, stream>>>(v, counter, out);

  void* args[6];
  args[0] = (void*)&x;
  args[1] = (void*)&y;
  args[2] = (void*)&u;
  args[3] = (void*)&v;
  args[4] = (void*)&out;
  args[5] = (void*)&counter;
  hipLaunchCooperativeKernel((void*)sinkhorn_main, dim3(NBLK), dim3(TPB),
                             args, 0, stream);
}

// Round 3
// 743.498 us; speedup vs baseline: 3.4517x; 1.5176x over previous
//
#include <hip/hip_runtime.h>

// Sinkhorn, N=4096, D=2, P=1, eps=0.1, 50 iters — persistent cooperative kernel.
// u_i = eps*log_mu - eps*ln sum_j exp((v_j - C_ij)/eps); v symmetric with fresh u.
// Scaled space: arg2 = W_j - |RX_i - C0_j| - |RY_i - C1_j|, all values * log2(e)/eps.
//
// Round-3 changes vs round 2 (1031 us, VALUBusy 31%, Occ 24.5%):
//  - Tree grid-barrier: 16 leaf counters (256B apart) -> root -> epoch word.
//    Arrival RMWs and the release spin hit DIFFERENT lines (round-2 put 256
//    RMWs + 256 spinners on one MALL line -> ~7 us/barrier).
//  - TPB=1024, RPW=2 (same 16 rows/block, same 256 arrivals): 4 waves/SIMD
//    (launch_bounds caps VGPR at 128) to hide ~900-cyc coherent-load latency.
//  - 100 barriers instead of 101 (stream order covers init -> first stage).

#define NPTS    4096
#define EPS_F   0.1f
#define S_L2E   14.426950408889634f     /* log2(e)/eps */
#define INV_SL  0.0693147180559945f     /* 1/S_L2E = eps*ln2 */
#define A_LOGMU (-0.8317725207f)        /* eps * ln(1/N + 1e-8) */
#define N_ITER  50
#define NBLK    256
#define TPB     1024
#define WPB     (TPB / 64)              /* 16 waves/block */
#define RPW     2                       /* rows per wave (wave-pair shares rows) */
#define HALFC   2048                    /* columns per wave (pair splits 4096) */
#define NJT     (HALFC / 256)           /* 8 j-tiles of 64 lanes x 4 cols */
#define NLEAF   16
#define BSTRIDE 64                      /* ints between barrier words = 256 B */
#define BAR_INTS ((NLEAF + 2) * BSTRIDE)

typedef float f4u __attribute__((ext_vector_type(4), aligned(4)));

__device__ __forceinline__ float fexp2(float x) {
#if __has_builtin(__builtin_amdgcn_exp2f)
  return __builtin_amdgcn_exp2f(x);
#else
  float r;
  asm("v_exp_f32 %0, %1" : "=v"(r) : "v"(x));
  return r;
#endif
}

__device__ __forceinline__ float coh_load(const float* p) {
  return __hip_atomic_load(p, __ATOMIC_RELAXED, __HIP_MEMORY_SCOPE_AGENT);
}
__device__ __forceinline__ void coh_store(float* p, float x) {
  __hip_atomic_store(p, x, __ATOMIC_RELAXED, __HIP_MEMORY_SCOPE_AGENT);
}

__device__ __forceinline__ float wave_sum64(float x) {
#pragma unroll
  for (int off = 32; off > 0; off >>= 1) x += __shfl_xor(x, off, 64);
  return x;
}

// Tree barrier, all ops RELAXED AGENT (sc0/sc1 -> MALL coherence point, no
// cache-maintenance). __syncthreads before arrival drains this block's
// coherent u/v stores (s_waitcnt vmcnt(0) precedes s_barrier).
// leaf[b&15]: 16 RMWs each, parallel lines; 16 winners RMW root; last winner
// stores epoch=k; everyone spins on the (read-only, uncontended-by-RMW) epoch.
__device__ __forceinline__ void grid_barrier(int* bar, int k) {
  __syncthreads();
  if (threadIdx.x == 0) {
    int* leaf = bar + (blockIdx.x & (NLEAF - 1)) * BSTRIDE;
    const int old = __hip_atomic_fetch_add(leaf, 1, __ATOMIC_RELAXED,
                                           __HIP_MEMORY_SCOPE_AGENT);
    if (old == NLEAF * k - 1) {
      int* root = bar + NLEAF * BSTRIDE;
      const int ro = __hip_atomic_fetch_add(root, 1, __ATOMIC_RELAXED,
                                            __HIP_MEMORY_SCOPE_AGENT);
      if (ro == NLEAF * k - 1)
        __hip_atomic_store(bar + (NLEAF + 1) * BSTRIDE, k, __ATOMIC_RELAXED,
                           __HIP_MEMORY_SCOPE_AGENT);
    }
    while (__hip_atomic_load(bar + (NLEAF + 1) * BSTRIDE, __ATOMIC_RELAXED,
                             __HIP_MEMORY_SCOPE_AGENT) < k)
      __builtin_amdgcn_s_sleep(2);
  }
  __syncthreads();
}

// Stage win (coherent) + column coords (plain, L2-cached) into LDS, scaled.
// 4 consecutive cols per thread; b128 LDS writes.
__device__ __forceinline__ void stage(const float* __restrict__ win,
                                      const float* __restrict__ colp,
                                      float* __restrict__ sW,
                                      float* __restrict__ sC0,
                                      float* __restrict__ sC1, int tid) {
  const int c = tid * 4;
  const float w0 = coh_load(win + c + 0), w1 = coh_load(win + c + 1);
  const float w2 = coh_load(win + c + 2), w3 = coh_load(win + c + 3);
  const float4 a = ((const float4*)colp)[(c >> 1) + 0];  // (x0,y0,x1,y1)
  const float4 b = ((const float4*)colp)[(c >> 1) + 1];  // (x2,y2,x3,y3)
  float4 W, C0, C1;
  W.x = w0 * S_L2E;  W.y = w1 * S_L2E;  W.z = w2 * S_L2E;  W.w = w3 * S_L2E;
  C0.x = a.x * S_L2E; C0.y = a.z * S_L2E; C0.z = b.x * S_L2E; C0.w = b.z * S_L2E;
  C1.x = a.y * S_L2E; C1.y = a.w * S_L2E; C1.z = b.y * S_L2E; C1.w = b.w * S_L2E;
  *(float4*)(sW + c)  = W;
  *(float4*)(sC0 + c) = C0;
  *(float4*)(sC1 + c) = C1;
  __syncthreads();
}

// One half-iteration: this wave's RPW rows x its half of the columns.
// Wave pairs (2p, 2p+1) share rows, split columns; tid<16 combine + write.
__device__ __forceinline__ void phase(const float* __restrict__ rx,
                                      const float* __restrict__ ry,
                                      const float* __restrict__ sW,
                                      const float* __restrict__ sC0,
                                      const float* __restrict__ sC1,
                                      float (*sPart)[RPW],
                                      float* __restrict__ wout,
                                      int row0blk, int wv, int lane, int tid) {
  const int base = (wv & 1) * HALFC + lane * 4;
  float acc0 = 0.f, acc1 = 0.f;
#pragma unroll
  for (int jt = 0; jt < NJT; ++jt) {
    const int j = base + jt * 256;
    const float4 W  = *(const float4*)(sW + j);
    const float4 C0 = *(const float4*)(sC0 + j);
    const float4 C1 = *(const float4*)(sC1 + j);
    {
      const float a0 = (W.x - fabsf(rx[0] - C0.x)) - fabsf(ry[0] - C1.x);
      const float a1 = (W.y - fabsf(rx[0] - C0.y)) - fabsf(ry[0] - C1.y);
      const float a2 = (W.z - fabsf(rx[0] - C0.z)) - fabsf(ry[0] - C1.z);
      const float a3 = (W.w - fabsf(rx[0] - C0.w)) - fabsf(ry[0] - C1.w);
      acc0 += (fexp2(a0) + fexp2(a1)) + (fexp2(a2) + fexp2(a3));
    }
    {
      const float a0 = (W.x - fabsf(rx[1] - C0.x)) - fabsf(ry[1] - C1.x);
      const float a1 = (W.y - fabsf(rx[1] - C0.y)) - fabsf(ry[1] - C1.y);
      const float a2 = (W.z - fabsf(rx[1] - C0.z)) - fabsf(ry[1] - C1.z);
      const float a3 = (W.w - fabsf(rx[1] - C0.w)) - fabsf(ry[1] - C1.w);
      acc1 += (fexp2(a0) + fexp2(a1)) + (fexp2(a2) + fexp2(a3));
    }
  }
  const float S0 = wave_sum64(acc0);
  const float S1 = wave_sum64(acc1);
  if (lane == 0) { sPart[wv][0] = S0; sPart[wv][1] = S1; }
  __syncthreads();
  if (tid < 16) {
    const int p = tid >> 1, r = tid & 1;
    const float S = sPart[2 * p][r] + sPart[2 * p + 1][r];
    coh_store(wout + row0blk + p * RPW + r, A_LOGMU - EPS_F * __logf(S));
  }
}

__global__ void __launch_bounds__(TPB, 4)
sinkhorn_main(const float* __restrict__ x, const float* __restrict__ y,
              float* __restrict__ u, float* __restrict__ v,
              float* __restrict__ out, int* __restrict__ bar) {
  __shared__ float sW[NPTS], sC0[NPTS], sC1[NPTS];
  __shared__ float sPart[WPB][RPW];
  __shared__ float sCost[WPB];

  const int tid  = threadIdx.x;
  const int wv   = tid >> 6;
  const int lane = tid & 63;
  const int row0blk = blockIdx.x * (WPB / 2) * RPW;        // 16 rows per block
  const int row0 = row0blk + (wv >> 1) * RPW;              // this wave's rows

  float rxu[RPW], ryu[RPW], rxv[RPW], ryv[RPW];
#pragma unroll
  for (int r = 0; r < RPW; ++r) {
    const float2 xr = ((const float2*)x)[row0 + r];
    const float2 yr = ((const float2*)y)[row0 + r];
    rxu[r] = xr.x * S_L2E;  ryu[r] = xr.y * S_L2E;
    rxv[r] = yr.x * S_L2E;  ryv[r] = yr.y * S_L2E;
  }

  int k = 0;
  for (int it = 0; it < N_ITER; ++it) {
    stage(v, y, sW, sC0, sC1, tid);                         // cols = y, win = v
    phase(rxu, ryu, sW, sC0, sC1, sPart, u, row0blk, wv, lane, tid);
    grid_barrier(bar, ++k);
    stage(u, x, sW, sC0, sC1, tid);                         // cols = x, win = u
    phase(rxv, ryv, sW, sC0, sC1, sPart, v, row0blk, wv, lane, tid);
    grid_barrier(bar, ++k);
  }
  stage(v, y, sW, sC0, sC1, tid);                           // final v, y cols

  // ---- output: out[0]=cost, out[1..]=pi, out[1+N*N..]=C ----
  float* __restrict__ pi = out + 1;
  float* __restrict__ cm = out + 1 + (size_t)NPTS * NPTS;
  float uu[RPW];
#pragma unroll
  for (int r = 0; r < RPW; ++r) uu[r] = coh_load(u + row0 + r) * S_L2E;

  const int base = (wv & 1) * HALFC + lane * 4;
  float costacc = 0.f;
#pragma unroll 2
  for (int jt = 0; jt < NJT; ++jt) {
    const int j = base + jt * 256;
    const float4 W  = *(const float4*)(sW + j);
    const float4 C0 = *(const float4*)(sC0 + j);
    const float4 C1 = *(const float4*)(sC1 + j);
#pragma unroll
    for (int r = 0; r < RPW; ++r) {
      const float s0 = fabsf(rxu[r] - C0.x) + fabsf(ryu[r] - C1.x);
      const float s1 = fabsf(rxu[r] - C0.y) + fabsf(ryu[r] - C1.y);
      const float s2 = fabsf(rxu[r] - C0.z) + fabsf(ryu[r] - C1.z);
      const float s3 = fabsf(rxu[r] - C0.w) + fabsf(ryu[r] - C1.w);
      const float p0 = fexp2((uu[r] + W.x) - s0);
      const float p1 = fexp2((uu[r] + W.y) - s1);
      const float p2 = fexp2((uu[r] + W.z) - s2);
      const float p3 = fexp2((uu[r] + W.w) - s3);
      costacc = fmaf(p0, s0, costacc);
      costacc = fmaf(p1, s1, costacc);
      costacc = fmaf(p2, s2, costacc);
      costacc = fmaf(p3, s3, costacc);
      const size_t off = (size_t)(row0 + r) * NPTS + j;
      f4u pv; pv.x = p0; pv.y = p1; pv.z = p2; pv.w = p3;
      f4u cv; cv.x = s0 * INV_SL; cv.y = s1 * INV_SL;
      cv.z = s2 * INV_SL; cv.w = s3 * INV_SL;
      *(f4u*)(pi + off) = pv;   // out+1 base is 4B-aligned; f4u is aligned(4)
      *(f4u*)(cm + off) = cv;
    }
  }
  const float cw = wave_sum64(costacc);
  if (lane == 0) sCost[wv] = cw;
  __syncthreads();
  if (tid == 0) {
    float c = 0.f;
#pragma unroll
    for (int w = 0; w < WPB; ++w) c += sCost[w];
    atomicAdd(out, c * INV_SL);
  }
}

__global__ void sinkhorn_init(float* __restrict__ v, int* __restrict__ bar,
                              float* __restrict__ out) {
  const int i = blockIdx.x * blockDim.x + threadIdx.x;
  if (i < NPTS) coh_store(v + i, 0.f);
  if (i < BAR_INTS)
    __hip_atomic_store(bar + i, 0, __ATOMIC_RELAXED, __HIP_MEMORY_SCOPE_AGENT);
  if (i == 0) out[0] = 0.f;
}

extern "C" void kernel_launch(void* const* d_in, const int* in_sizes, int n_in,
                              void* d_out, int out_size, void* d_ws, size_t ws_size,
                              hipStream_t stream) {
  const float* x = (const float*)d_in[0];
  const float* y = (const float*)d_in[1];
  float* u = (float*)d_ws;
  float* v = u + NPTS;
  int* bar = (int*)(v + NPTS);
  float* out = (float*)d_out;

  sinkhorn_init<<<dim3(16), dim3(256), 0, stream>>>(v, bar, out);

  void* args[6];
  args[0] = (void*)&x;
  args[1] = (void*)&y;
  args[2] = (void*)&u;
  args[3] = (void*)&v;
  args[4] = (void*)&out;
  args[5] = (void*)&bar;
  hipLaunchCooperativeKernel((void*)sinkhorn_main, dim3(NBLK), dim3(TPB),
                             args, 0, stream);
}